// Round 1
// baseline (163.302 us; speedup 1.0000x reference)
//
#include <hip/hip_runtime.h>

#define C_    128
#define H_    100
#define W_    64
#define KH_   10
#define KW_   4
#define M_    160        // q rows (10*16)
#define K1_   5120       // C*KH*KW
#define HK_   91
#define WK_   61
#define JP_   5824       // 91*64 (wk padded to 64)
#define NZ    819200     // elements per input tensor
#define KS1   8          // k-split gemm1
#define KS2   8          // k-split gemm2

typedef __attribute__((ext_vector_type(8))) short short8;
typedef __attribute__((ext_vector_type(4))) short short4v;
typedef __attribute__((ext_vector_type(4))) float f32x4;

__device__ __forceinline__ unsigned short f2bf(float f) {
    // round-half-up f32 -> bf16 (bias negligible for this workload)
    unsigned int u = __float_as_uint(f);
    return (unsigned short)((u + 0x8000u) >> 16);
}

__device__ __forceinline__ f32x4 load4u(const float* p) {
    // 16B load with only 4B alignment guaranteed (legal on gfx950 global)
    f32x4 v; __builtin_memcpy(&v, p, 16); return v;
}

// ---------------------------------------------------------------------------
// pack: Qb[i][d] = bf16(q patch of z1) ; Z2s[kw][c][h][w] = bf16(z2[c][h][w+kw])
// ---------------------------------------------------------------------------
__global__ __launch_bounds__(256) void pack_kernel(const float* __restrict__ z1,
                                                   const float* __restrict__ z2,
                                                   unsigned short* __restrict__ Qb,
                                                   unsigned short* __restrict__ Z2s) {
    int tid = blockIdx.x * 256 + threadIdx.x;
    if (tid < NZ) {
        int i = tid / K1_, d = tid - i * K1_;
        int c = d / 40, rr = d - c * 40;
        int kh = rr >> 2, kw = rr & 3;
        int ih = i >> 4, iw = i & 15;
        Qb[tid] = f2bf(z1[c * 6400 + (ih * KH_ + kh) * W_ + iw * KW_ + kw]);
    } else {
        int t2 = tid - NZ;               // 0 .. 4*NZ-1
        int kw = t2 / NZ, r = t2 - kw * NZ;
        int w = r & 63;
        int wc = min(w + kw, 63);        // clamp; only pad columns ever see clamped data
        Z2s[t2] = f2bf(z2[r - w + wc]);
    }
}

// ---------------------------------------------------------------------------
// GEMM1: Sp[ksp][i][jp] = sum_{d in chunk} Q[i][d] * KV[jp][d]
// grid (KS1, 46): tile M=160 x N=128 (2 hk rows), K-chunk 640
// ---------------------------------------------------------------------------
__global__ __launch_bounds__(256, 3) void gemm1_kernel(const unsigned short* __restrict__ Qb,
                                                       const float* __restrict__ z2,
                                                       float* __restrict__ Sp) {
    __shared__ short As[160 * 40];   // Q tile   [i][k]  (pad stride 40)
    __shared__ short Bs[128 * 40];   // KV tile  [jp][k]
    const int t = threadIdx.x;
    const int ksp = blockIdx.x;      // 0..7
    const int hkt = blockIdx.y;      // 0..45
    const int kbase = ksp * 640;
    const int hk0 = hkt * 2;
    const int wave = t >> 6, lane = t & 63;
    const int mh = wave & 1, nh = wave >> 1;       // wave tile 80 x 64
    const int l15 = lane & 15, q = lane >> 4;

    f32x4 acc[5][4];
#pragma unroll
    for (int b = 0; b < 5; ++b)
#pragma unroll
        for (int n = 0; n < 4; ++n) acc[b][n] = (f32x4){0.f, 0.f, 0.f, 0.f};

    for (int it = 0; it < 20; ++it) {
        int k0 = kbase + it * 32;
        __syncthreads();
        // stage A: 160 rows x 32 k, 640 16B chunks
#pragma unroll
        for (int s = 0; s < 3; ++s) {
            int cs = t + s * 256;
            if (cs < 640) {
                int row = cs >> 2, kq = (cs & 3) << 3;
                *(short8*)&As[row * 40 + kq] = *(const short8*)(Qb + row * K1_ + k0 + kq);
            }
        }
        // stage B: 128 jp x 32 d, unit = (jp, d-quad): contiguous 4 floats of z2
#pragma unroll
        for (int s = 0; s < 4; ++s) {
            int u = t + s * 256;
            int jp = u >> 3, dq = u & 7;
            int d0 = k0 + dq * 4;                 // multiple of 4 -> kw=0 start
            int c = d0 / 40, rr = d0 - c * 40;
            int kh = rr >> 2;
            int hk = hk0 + (jp >> 6), wk = jp & 63;
            int src = c * 6400 + (hk + kh) * W_ + wk;
            src = min(src, NZ - 4);               // only pad columns get clamped
            f32x4 v = load4u(z2 + src);
            short4v b4;
            b4.x = (short)f2bf(v.x); b4.y = (short)f2bf(v.y);
            b4.z = (short)f2bf(v.z); b4.w = (short)f2bf(v.w);
            *(short4v*)&Bs[jp * 40 + dq * 4] = b4;
        }
        __syncthreads();
        short8 af[5], bf[4];
#pragma unroll
        for (int b = 0; b < 5; ++b)
            af[b] = *(const short8*)&As[((mh * 5 + b) * 16 + l15) * 40 + q * 8];
#pragma unroll
        for (int n = 0; n < 4; ++n)
            bf[n] = *(const short8*)&Bs[((nh * 4 + n) * 16 + l15) * 40 + q * 8];
#pragma unroll
        for (int b = 0; b < 5; ++b)
#pragma unroll
            for (int n = 0; n < 4; ++n)
                acc[b][n] = __builtin_amdgcn_mfma_f32_16x16x32_bf16(af[b], bf[n], acc[b][n], 0, 0, 0);
    }
    // epilogue: plain stores to this split's partial
    float* base = Sp + (size_t)ksp * (160 * JP_);
#pragma unroll
    for (int b = 0; b < 5; ++b) {
        int i0 = (mh * 5 + b) * 16 + q * 4;
#pragma unroll
        for (int n = 0; n < 4; ++n) {
            int jg = hkt * 128 + (nh * 4 + n) * 16 + l15;
            if (jg < JP_) {
#pragma unroll
                for (int r = 0; r < 4; ++r)
                    base[(size_t)(i0 + r) * JP_ + jg] = acc[b][n][r];
            }
        }
    }
}

// ---------------------------------------------------------------------------
// softmax: per q-row; sums KS1 partials, masks pad cols, writes bf16 attn
// ---------------------------------------------------------------------------
__global__ __launch_bounds__(256) void softmax_kernel(const float* __restrict__ Sp,
                                                      unsigned short* __restrict__ Atn) {
    const int i = blockIdx.x;
    const int t = threadIdx.x;
    const int wave = t >> 6, lane = t & 63;
    __shared__ float red[4];
    __shared__ float red2[4];
    float vals[23];
#pragma unroll
    for (int jj = 0; jj < 23; ++jj) {
        int jp = t + jj * 256;
        float v = -1e30f;
        if (jp < JP_ && (jp & 63) < WK_) {
            float s = 0.f;
#pragma unroll
            for (int p = 0; p < KS1; ++p)
                s += Sp[(size_t)p * (160 * JP_) + (size_t)i * JP_ + jp];
            v = s * (1.0f / 5120.0f);
        }
        vals[jj] = v;
    }
    float m = -1e30f;
#pragma unroll
    for (int jj = 0; jj < 23; ++jj) m = fmaxf(m, vals[jj]);
#pragma unroll
    for (int off = 32; off >= 1; off >>= 1) m = fmaxf(m, __shfl_xor(m, off));
    if (lane == 0) red[wave] = m;
    __syncthreads();
    m = fmaxf(fmaxf(red[0], red[1]), fmaxf(red[2], red[3]));

    float s = 0.f;
#pragma unroll
    for (int jj = 0; jj < 23; ++jj) {
        if (vals[jj] > -1e29f) { vals[jj] = __expf(vals[jj] - m); s += vals[jj]; }
        else vals[jj] = 0.f;
    }
#pragma unroll
    for (int off = 32; off >= 1; off >>= 1) s += __shfl_xor(s, off);
    if (lane == 0) red2[wave] = s;
    __syncthreads();
    float inv = 1.0f / (red2[0] + red2[1] + red2[2] + red2[3]);
#pragma unroll
    for (int jj = 0; jj < 23; ++jj) {
        int jp = t + jj * 256;
        if (jp < JP_) Atn[(size_t)i * JP_ + jp] = f2bf(vals[jj] * inv);
    }
}

// ---------------------------------------------------------------------------
// GEMM2: Op[ksp][d*160+i] = sum_{jp in chunk} KV[jp][d] * A[i][jp]
// grid (KS2, 40): tile M=128(d) x N=160(i), K over jp
// ---------------------------------------------------------------------------
__global__ __launch_bounds__(256, 3) void gemm2_kernel(const unsigned short* __restrict__ Atn,
                                                       const unsigned short* __restrict__ Z2s,
                                                       float* __restrict__ Op) {
    __shared__ short As[128 * 40];   // KV^T tile [d_local][jp_local]
    __shared__ short Bs[160 * 40];   // attn tile [i][jp_local]
    const int t = threadIdx.x;
    const int ksp = blockIdx.x;      // 0..7
    const int dt = blockIdx.y;       // 0..39
    const int dbase = dt * 128;
    const int it0 = (182 * ksp) >> 3;
    const int it1 = (182 * (ksp + 1)) >> 3;
    const int wave = t >> 6, lane = t & 63;
    const int mh = wave & 1, nh = wave >> 1;       // wave tile 64(d) x 80(i)
    const int l15 = lane & 15, q = lane >> 4;

    f32x4 acc[4][5];
#pragma unroll
    for (int m = 0; m < 4; ++m)
#pragma unroll
        for (int n = 0; n < 5; ++n) acc[m][n] = (f32x4){0.f, 0.f, 0.f, 0.f};

    for (int it = it0; it < it1; ++it) {
        int k0 = it * 32;            // jp base (stays within one hk 64-block half)
        __syncthreads();
        // stage B: attn rows, 160 x 32, 640 16B chunks
#pragma unroll
        for (int s = 0; s < 3; ++s) {
            int cs = t + s * 256;
            if (cs < 640) {
                int row = cs >> 2, kq = (cs & 3) << 3;
                *(short8*)&Bs[row * 40 + kq] = *(const short8*)(Atn + (size_t)row * JP_ + k0 + kq);
            }
        }
        // stage A: 128 d x 32 jp via shifted bf16 planes, aligned 16B loads
#pragma unroll
        for (int s = 0; s < 2; ++s) {
            int u = t + s * 256;
            int dl = u >> 2, jg = u & 3;
            int d = dbase + dl;
            int c = d / 40, rr = d - c * 40;
            int kh = rr >> 2, kw = rr & 3;
            int jp0 = k0 + jg * 8;
            int hk = jp0 >> 6, wk0 = jp0 & 63;
            int src = kw * NZ + c * 6400 + (hk + kh) * W_ + wk0;
            src = min(src, 4 * NZ - 8);
            *(short8*)&As[dl * 40 + jg * 8] = *(const short8*)(Z2s + src);
        }
        __syncthreads();
        short8 af[4], bf[5];
#pragma unroll
        for (int m = 0; m < 4; ++m)
            af[m] = *(const short8*)&As[(mh * 64 + m * 16 + l15) * 40 + q * 8];
#pragma unroll
        for (int n = 0; n < 5; ++n)
            bf[n] = *(const short8*)&Bs[((nh * 5 + n) * 16 + l15) * 40 + q * 8];
#pragma unroll
        for (int m = 0; m < 4; ++m)
#pragma unroll
            for (int n = 0; n < 5; ++n)
                acc[m][n] = __builtin_amdgcn_mfma_f32_16x16x32_bf16(af[m], bf[n], acc[m][n], 0, 0, 0);
    }
    float* base = Op + (size_t)ksp * ((size_t)K1_ * 160);
#pragma unroll
    for (int m = 0; m < 4; ++m) {
        int d0 = dbase + mh * 64 + m * 16 + q * 4;
#pragma unroll
        for (int n = 0; n < 5; ++n) {
            int i = (nh * 5 + n) * 16 + l15;
#pragma unroll
            for (int r = 0; r < 4; ++r)
                base[(size_t)(d0 + r) * 160 + i] = acc[m][n][r];
        }
    }
}

// ---------------------------------------------------------------------------
// reduce: out[c][ih*10+kh][iw*4+kw] = sum_p Op[p][d*160+i]
// ---------------------------------------------------------------------------
__global__ __launch_bounds__(256) void reduce_kernel(const float* __restrict__ Op,
                                                     float* __restrict__ out) {
    int tid = blockIdx.x * 256 + threadIdx.x;   // < 819200
    int d = tid / 160, i = tid - d * 160;
    float s = 0.f;
#pragma unroll
    for (int p = 0; p < KS2; ++p) s += Op[(size_t)p * NZ + tid];
    int c = d / 40, rr = d - c * 40;
    int kh = rr >> 2, kw = rr & 3;
    int ih = i >> 4, iw = i & 15;
    out[c * 6400 + (ih * KH_ + kh) * W_ + iw * KW_ + kw] = s;
}

extern "C" void kernel_launch(void* const* d_in, const int* in_sizes, int n_in,
                              void* d_out, int out_size, void* d_ws, size_t ws_size,
                              hipStream_t stream) {
    const float* z1 = (const float*)d_in[0];
    const float* z2 = (const float*)d_in[1];
    float* out = (float*)d_out;

    char* w = (char*)d_ws;
    unsigned short* Qb  = (unsigned short*)(w);                          // 1,638,400 B
    unsigned short* Z2s = (unsigned short*)(w + 1638400);                // 6,553,600 B
    unsigned short* Atn = (unsigned short*)(w + 1638400 + 6553600);      // 1,863,680 B
    float* Sp = (float*)(w + 1638400 + 6553600 + 1863680);               // 29,818,880 B
    float* Op = Sp;  // reused (26,214,400 B <= Sp region); total ws ~38 MB

    pack_kernel<<<16000, 256, 0, stream>>>(z1, z2, Qb, Z2s);
    gemm1_kernel<<<dim3(KS1, 46), 256, 0, stream>>>(Qb, z2, Sp);
    softmax_kernel<<<160, 256, 0, stream>>>(Sp, Atn);
    gemm2_kernel<<<dim3(KS2, 40), 256, 0, stream>>>(Atn, Z2s, Op);
    reduce_kernel<<<3200, 256, 0, stream>>>(Op, out);
}

// Round 2
// 157.333 us; speedup vs baseline: 1.0379x; 1.0379x over previous
//
#include <hip/hip_runtime.h>

#define C_    128
#define H_    100
#define W_    64
#define KH_   10
#define KW_   4
#define M_    160        // q rows (10*16)
#define K1_   5120       // C*KH*KW
#define HK_   91
#define WK_   61
#define JP_   5824       // 91*64 (wk padded to 64)
#define NZ    819200     // elements per input tensor
#define KS1   8          // k-split gemm1
#define KS2   8          // k-split gemm2

typedef __attribute__((ext_vector_type(8))) short short8;
typedef __attribute__((ext_vector_type(4))) float f32x4;

__device__ __forceinline__ unsigned short f2bf(float f) {
    unsigned int u = __float_as_uint(f);
    return (unsigned short)((u + 0x8000u) >> 16);
}

// ---------------------------------------------------------------------------
// pack (fused, one 16B store per thread):
//   Qb[i][d]            bf16 Q patches           (NZ elems)
//   Z2s[kw][c][h][w]    bf16 shifted planes      (4*NZ)    -> gemm2 gather
//   X[c][h][w][8]       bf16 {row h w..w+3, row h+1 w..w+3} (8*NZ) -> gemm1 gather
// total threads = NZ/8 + 4*NZ/8 + NZ = 1,331,200 = 5200*256
// ---------------------------------------------------------------------------
__global__ __launch_bounds__(256) void pack_kernel(const float* __restrict__ z1,
                                                   const float* __restrict__ z2,
                                                   unsigned short* __restrict__ Qb,
                                                   unsigned short* __restrict__ Z2s,
                                                   unsigned short* __restrict__ X) {
    int tid = blockIdx.x * 256 + threadIdx.x;
    if (tid < 102400) {                       // --- Q octs ---
        int o = tid;
        int i = o / 640, od = o - i * 640;
        int d0 = od * 8;
        int c = d0 / 40, rr = d0 - c * 40;
        int kh0 = rr >> 2;                    // even
        int ih = i >> 4, iw = i & 15;
        int a0 = c * 6400 + (ih * KH_ + kh0) * W_ + iw * KW_;
        unsigned short v[8];
#pragma unroll
        for (int s = 0; s < 4; ++s) v[s] = f2bf(z1[a0 + s]);
#pragma unroll
        for (int s = 0; s < 4; ++s) v[4 + s] = f2bf(z1[a0 + W_ + s]);
        *(short8*)(Qb + (size_t)i * K1_ + d0) = *(short8*)v;
    } else if (tid < 512000) {                // --- Z2s octs ---
        int o = tid - 102400;
        int kw = o / 102400, r8 = o - kw * 102400;
        int e0 = r8 * 8;
        int w0 = e0 & 63, rowbase = e0 - w0;
        unsigned short v[8];
#pragma unroll
        for (int s = 0; s < 8; ++s) v[s] = f2bf(z2[rowbase + min(w0 + s + kw, 63)]);
        *(short8*)(Z2s + (size_t)kw * NZ + e0) = *(short8*)v;
    } else {                                  // --- X triples ---
        int o = tid - 512000;                 // o = (c*100+h)*64 + w
        int w = o & 63, ch = o >> 6;
        int h = ch % 100;
        int ch2 = (h < 99) ? ch + 1 : ch;
        unsigned short v[8];
#pragma unroll
        for (int s = 0; s < 4; ++s) v[s] = f2bf(z2[ch * 64 + min(w + s, 63)]);
#pragma unroll
        for (int s = 0; s < 4; ++s) v[4 + s] = f2bf(z2[ch2 * 64 + min(w + s, 63)]);
        *(short8*)(X + (size_t)o * 8) = *(short8*)v;
    }
}

// ---------------------------------------------------------------------------
// GEMM1: Sp[ksp][i][jp] = sum_{d in chunk} Q[i][d] * KV[jp][d]
// grid (KS1, 46): tile M=160 x N=128 (2 hk rows), K-chunk 640, BK=32
// B-tile k-octs come straight from X as one aligned 16B load each.
// ---------------------------------------------------------------------------
__global__ __launch_bounds__(256) void gemm1_kernel(const unsigned short* __restrict__ Qb,
                                                    const unsigned short* __restrict__ X,
                                                    float* __restrict__ Sp) {
    __shared__ short As[160 * 40];   // Q tile  [i][k]   stride 40
    __shared__ short Bs[128 * 48];   // KV tile [jp][k]  stride 48 (4-way max)
    const int t = threadIdx.x;
    const int ksp = blockIdx.x;      // 0..7
    const int hkt = blockIdx.y;      // 0..45
    const int kbase = ksp * 640;
    const int hk0 = hkt * 2;
    const int wave = t >> 6, lane = t & 63;
    const int mh = wave & 1, nh = wave >> 1;       // wave tile 80 x 64
    const int l15 = lane & 15, q = lane >> 4;

    f32x4 acc[5][4];
#pragma unroll
    for (int b = 0; b < 5; ++b)
#pragma unroll
        for (int n = 0; n < 4; ++n) acc[b][n] = (f32x4){0.f, 0.f, 0.f, 0.f};

    for (int it = 0; it < 20; ++it) {
        int k0 = kbase + it * 32;
        __syncthreads();
        // stage A: 160 rows x 32 k = 640 16B chunks
#pragma unroll
        for (int s = 0; s < 3; ++s) {
            int cs = t + s * 256;
            if (cs < 640) {
                int row = cs >> 2, kq = (cs & 3) << 3;
                *(short8*)&As[row * 40 + kq] = *(const short8*)(Qb + (size_t)row * K1_ + k0 + kq);
            }
        }
        // stage B: 128 jp x 4 k-octs = 512 aligned 16B loads from X (lane-coalesced in jp)
#pragma unroll
        for (int s = 0; s < 2; ++s) {
            int u = t + s * 256;
            int jp = u & 127, oct = u >> 7;
            int d0 = k0 + oct * 8;               // multiple of 8
            int c = d0 / 40, rr = d0 - c * 40;
            int kh0 = rr >> 2;                   // even
            int hk = hk0 + (jp >> 6), wk = jp & 63;
            int src = ((c * 100 + hk + kh0) * 64 + wk) * 8;   // always in-bounds (h<=99)
            *(short8*)&Bs[jp * 48 + oct * 8] = *(const short8*)(X + src);
        }
        __syncthreads();
        short8 af[5], bf[4];
#pragma unroll
        for (int b = 0; b < 5; ++b)
            af[b] = *(const short8*)&As[((mh * 5 + b) * 16 + l15) * 40 + q * 8];
#pragma unroll
        for (int n = 0; n < 4; ++n)
            bf[n] = *(const short8*)&Bs[((nh * 4 + n) * 16 + l15) * 48 + q * 8];
#pragma unroll
        for (int b = 0; b < 5; ++b)
#pragma unroll
            for (int n = 0; n < 4; ++n)
                acc[b][n] = __builtin_amdgcn_mfma_f32_16x16x32_bf16(af[b], bf[n], acc[b][n], 0, 0, 0);
    }
    float* base = Sp + (size_t)ksp * (160 * JP_);
#pragma unroll
    for (int b = 0; b < 5; ++b) {
        int i0 = (mh * 5 + b) * 16 + q * 4;
#pragma unroll
        for (int n = 0; n < 4; ++n) {
            int jg = hkt * 128 + (nh * 4 + n) * 16 + l15;
            if (jg < JP_) {
#pragma unroll
                for (int r = 0; r < 4; ++r)
                    base[(size_t)(i0 + r) * JP_ + jg] = acc[b][n][r];
            }
        }
    }
}

// ---------------------------------------------------------------------------
// softmax: per q-row; sums KS1 partials, masks pad cols, writes bf16 attn
// ---------------------------------------------------------------------------
__global__ __launch_bounds__(256) void softmax_kernel(const float* __restrict__ Sp,
                                                      unsigned short* __restrict__ Atn) {
    const int i = blockIdx.x;
    const int t = threadIdx.x;
    const int wave = t >> 6, lane = t & 63;
    __shared__ float red[4];
    __shared__ float red2[4];
    float vals[23];
#pragma unroll
    for (int jj = 0; jj < 23; ++jj) {
        int jp = t + jj * 256;
        float v = -1e30f;
        if (jp < JP_ && (jp & 63) < WK_) {
            float s = 0.f;
#pragma unroll
            for (int p = 0; p < KS1; ++p)
                s += Sp[(size_t)p * (160 * JP_) + (size_t)i * JP_ + jp];
            v = s * (1.0f / 5120.0f);
        }
        vals[jj] = v;
    }
    float m = -1e30f;
#pragma unroll
    for (int jj = 0; jj < 23; ++jj) m = fmaxf(m, vals[jj]);
#pragma unroll
    for (int off = 32; off >= 1; off >>= 1) m = fmaxf(m, __shfl_xor(m, off));
    if (lane == 0) red[wave] = m;
    __syncthreads();
    m = fmaxf(fmaxf(red[0], red[1]), fmaxf(red[2], red[3]));

    float s = 0.f;
#pragma unroll
    for (int jj = 0; jj < 23; ++jj) {
        if (vals[jj] > -1e29f) { vals[jj] = __expf(vals[jj] - m); s += vals[jj]; }
        else vals[jj] = 0.f;
    }
#pragma unroll
    for (int off = 32; off >= 1; off >>= 1) s += __shfl_xor(s, off);
    if (lane == 0) red2[wave] = s;
    __syncthreads();
    float inv = 1.0f / (red2[0] + red2[1] + red2[2] + red2[3]);
#pragma unroll
    for (int jj = 0; jj < 23; ++jj) {
        int jp = t + jj * 256;
        if (jp < JP_) Atn[(size_t)i * JP_ + jp] = f2bf(vals[jj] * inv);
    }
}

// ---------------------------------------------------------------------------
// GEMM2: Op[ksp][d*160+i] = sum_{jp in chunk} KV[jp][d] * A[i][jp]
// grid (KS2, 40): tile M=128(d) x N=160(i), K over jp, BK=32
// ---------------------------------------------------------------------------
__global__ __launch_bounds__(256) void gemm2_kernel(const unsigned short* __restrict__ Atn,
                                                    const unsigned short* __restrict__ Z2s,
                                                    float* __restrict__ Op) {
    __shared__ short As[128 * 40];   // KV^T tile [d_local][jp_local]
    __shared__ short Bs[160 * 40];   // attn tile [i][jp_local]
    const int t = threadIdx.x;
    const int ksp = blockIdx.x;      // 0..7
    const int dt = blockIdx.y;       // 0..39
    const int dbase = dt * 128;
    const int it0 = (182 * ksp) >> 3;
    const int it1 = (182 * (ksp + 1)) >> 3;
    const int wave = t >> 6, lane = t & 63;
    const int mh = wave & 1, nh = wave >> 1;       // wave tile 64(d) x 80(i)
    const int l15 = lane & 15, q = lane >> 4;

    f32x4 acc[4][5];
#pragma unroll
    for (int m = 0; m < 4; ++m)
#pragma unroll
        for (int n = 0; n < 5; ++n) acc[m][n] = (f32x4){0.f, 0.f, 0.f, 0.f};

    for (int it = it0; it < it1; ++it) {
        int k0 = it * 32;            // jp base
        __syncthreads();
        // stage B: attn rows, 160 x 32 = 640 16B chunks
#pragma unroll
        for (int s = 0; s < 3; ++s) {
            int cs = t + s * 256;
            if (cs < 640) {
                int row = cs >> 2, kq = (cs & 3) << 3;
                *(short8*)&Bs[row * 40 + kq] = *(const short8*)(Atn + (size_t)row * JP_ + k0 + kq);
            }
        }
        // stage A: 128 d x 32 jp via shifted bf16 planes, aligned 16B loads
#pragma unroll
        for (int s = 0; s < 2; ++s) {
            int u = t + s * 256;
            int dl = u >> 2, jg = u & 3;
            int d = dbase + dl;
            int c = d / 40, rr = d - c * 40;
            int kh = rr >> 2, kw = rr & 3;
            int jp0 = k0 + jg * 8;
            int hk = jp0 >> 6, wk0 = jp0 & 63;   // wk0 <= 56, hk <= 90: in-bounds
            int src = kw * NZ + c * 6400 + (hk + kh) * W_ + wk0;
            *(short8*)&As[dl * 40 + jg * 8] = *(const short8*)(Z2s + src);
        }
        __syncthreads();
        short8 af[4], bf[5];
#pragma unroll
        for (int m = 0; m < 4; ++m)
            af[m] = *(const short8*)&As[(mh * 64 + m * 16 + l15) * 40 + q * 8];
#pragma unroll
        for (int n = 0; n < 5; ++n)
            bf[n] = *(const short8*)&Bs[((nh * 5 + n) * 16 + l15) * 40 + q * 8];
#pragma unroll
        for (int m = 0; m < 4; ++m)
#pragma unroll
            for (int n = 0; n < 5; ++n)
                acc[m][n] = __builtin_amdgcn_mfma_f32_16x16x32_bf16(af[m], bf[n], acc[m][n], 0, 0, 0);
    }
    float* base = Op + (size_t)ksp * ((size_t)K1_ * 160);
#pragma unroll
    for (int m = 0; m < 4; ++m) {
        int d0 = dbase + mh * 64 + m * 16 + q * 4;
#pragma unroll
        for (int n = 0; n < 5; ++n) {
            int i = (nh * 5 + n) * 16 + l15;
#pragma unroll
            for (int r = 0; r < 4; ++r)
                base[(size_t)(d0 + r) * 160 + i] = acc[m][n][r];
        }
    }
}

// ---------------------------------------------------------------------------
// reduce: out[c][ih*10+kh][iw*4+kw] = sum_p Op[p][d*160+i]
// ---------------------------------------------------------------------------
__global__ __launch_bounds__(256) void reduce_kernel(const float* __restrict__ Op,
                                                     float* __restrict__ out) {
    int tid = blockIdx.x * 256 + threadIdx.x;   // < 819200
    int d = tid / 160, i = tid - d * 160;
    float s = 0.f;
#pragma unroll
    for (int p = 0; p < KS2; ++p) s += Op[(size_t)p * NZ + tid];
    int c = d / 40, rr = d - c * 40;
    int kh = rr >> 2, kw = rr & 3;
    int ih = i >> 4, iw = i & 15;
    out[c * 6400 + (ih * KH_ + kh) * W_ + iw * KW_ + kw] = s;
}

extern "C" void kernel_launch(void* const* d_in, const int* in_sizes, int n_in,
                              void* d_out, int out_size, void* d_ws, size_t ws_size,
                              hipStream_t stream) {
    const float* z1 = (const float*)d_in[0];
    const float* z2 = (const float*)d_in[1];
    float* out = (float*)d_out;

    char* w = (char*)d_ws;
    unsigned short* Qb  = (unsigned short*)(w);                                   // 1,638,400 B
    unsigned short* Z2s = (unsigned short*)(w + 1638400);                         // 6,553,600 B
    unsigned short* X   = (unsigned short*)(w + 1638400 + 6553600);               // 13,107,200 B
    unsigned short* Atn = (unsigned short*)(w + 1638400 + 6553600 + 13107200);    // 1,863,680 B
    float* Sp = (float*)(w + 1638400 + 6553600 + 13107200 + 1863680);             // 29,818,880 B
    float* Op = Sp;  // reused

    pack_kernel<<<5200, 256, 0, stream>>>(z1, z2, Qb, Z2s, X);
    gemm1_kernel<<<dim3(KS1, 46), 256, 0, stream>>>(Qb, X, Sp);
    softmax_kernel<<<160, 256, 0, stream>>>(Sp, Atn);
    gemm2_kernel<<<dim3(KS2, 40), 256, 0, stream>>>(Atn, Z2s, Op);
    reduce_kernel<<<3200, 256, 0, stream>>>(Op, out);
}

// Round 3
// 146.886 us; speedup vs baseline: 1.1118x; 1.0711x over previous
//
#include <hip/hip_runtime.h>

#define KH_   10
#define KW_   4
#define W_    64
#define K1_   5120       // C*KH*KW
#define WK_   61
#define JP_   5824       // 91*64
#define NZ    819200
#define KS1   16         // k-split gemm1 (chunk 320, 10 iters of 32)
#define KS2   16         // k-split gemm2 (182 iters split ~11.4)

typedef __attribute__((ext_vector_type(8))) short short8;
typedef __attribute__((ext_vector_type(4))) short short4v;
typedef __attribute__((ext_vector_type(4))) float f32x4;

__device__ __forceinline__ unsigned short f2bf(float f) {
    unsigned int u = __float_as_uint(f);
    return (unsigned short)((u + 0x8000u) >> 16);
}

// ---------------------------------------------------------------------------
// pack:
//   Qb2[ko][i][8]     bf16 Q in MFMA-A fragment layout (ko = d/8)   102400 octs
//   Z2s[kw][c][h][w]  bf16 shifted planes (gemm2 KV^T gather)       409600 octs
//   X[c][h][w][8]     bf16 {row h w..w+3, row h+1 w..w+3} (gemm1 B) 819200 octs
// ---------------------------------------------------------------------------
__global__ __launch_bounds__(256) void pack_kernel(const float* __restrict__ z1,
                                                   const float* __restrict__ z2,
                                                   unsigned short* __restrict__ Qb2,
                                                   unsigned short* __restrict__ Z2s,
                                                   unsigned short* __restrict__ X) {
    int tid = blockIdx.x * 256 + threadIdx.x;
    if (tid < 102400) {                       // --- Qb2 octs (frag layout) ---
        int ko = tid / 160, i = tid - ko * 160;
        int d0 = ko * 8;
        int c = d0 / 40, rr = d0 - c * 40;
        int kh0 = rr >> 2;                    // even
        int ih = i >> 4, iw = i & 15;
        int a0 = c * 6400 + (ih * KH_ + kh0) * W_ + iw * KW_;
        unsigned short v[8];
#pragma unroll
        for (int s = 0; s < 4; ++s) v[s] = f2bf(z1[a0 + s]);
#pragma unroll
        for (int s = 0; s < 4; ++s) v[4 + s] = f2bf(z1[a0 + W_ + s]);
        *(short8*)(Qb2 + (size_t)tid * 8) = *(short8*)v;
    } else if (tid < 512000) {                // --- Z2s octs ---
        int o = tid - 102400;
        int kw = o / 102400, r8 = o - kw * 102400;
        int e0 = r8 * 8;
        int w0 = e0 & 63, rowbase = e0 - w0;
        unsigned short v[8];
#pragma unroll
        for (int s = 0; s < 8; ++s) v[s] = f2bf(z2[rowbase + min(w0 + s + kw, 63)]);
        *(short8*)(Z2s + (size_t)kw * NZ + e0) = *(short8*)v;
    } else {                                  // --- X octs ---
        int o = tid - 512000;                 // o = (c*100+h)*64 + w
        int w = o & 63, ch = o >> 6;
        int h = ch % 100;
        int ch2 = (h < 99) ? ch + 1 : ch;
        unsigned short v[8];
#pragma unroll
        for (int s = 0; s < 4; ++s) v[s] = f2bf(z2[ch * 64 + min(w + s, 63)]);
#pragma unroll
        for (int s = 0; s < 4; ++s) v[4 + s] = f2bf(z2[ch2 * 64 + min(w + s, 63)]);
        *(short8*)(X + (size_t)o * 8) = *(short8*)v;
    }
}

// ---------------------------------------------------------------------------
// GEMM1: no LDS, no barriers. grid (KS1, 46); tile 160x128 (2 hk rows).
// A-frags from Qb2 (fragment layout), B-frags from X (fragment layout).
// ---------------------------------------------------------------------------
__global__ __launch_bounds__(256) void gemm1_kernel(const unsigned short* __restrict__ Qb2,
                                                    const unsigned short* __restrict__ X,
                                                    float* __restrict__ Sp) {
    const int t = threadIdx.x;
    const int ksp = blockIdx.x;      // 0..15
    const int hkt = blockIdx.y;      // 0..45
    const int hk0 = hkt * 2;
    const int wave = t >> 6, lane = t & 63;
    const int mh = wave & 1, nh = wave >> 1;       // wave tile 80 x 64
    const int l15 = lane & 15, q = lane >> 4;

    // lane-invariant B column offsets
    int band[4], wk[4];
#pragma unroll
    for (int n = 0; n < 4; ++n) {
        int jpn = (nh * 4 + n) * 16 + l15;
        band[n] = jpn >> 6;          // 0 or 1
        wk[n]   = jpn & 63;
    }
    int rowA[5];
#pragma unroll
    for (int b = 0; b < 5; ++b) rowA[b] = (mh * 5 + b) * 16 + l15;

    f32x4 acc[5][4];
#pragma unroll
    for (int b = 0; b < 5; ++b)
#pragma unroll
        for (int n = 0; n < 4; ++n) acc[b][n] = (f32x4){0.f, 0.f, 0.f, 0.f};

    for (int it = 0; it < 10; ++it) {
        // A fragments: oct index (ksp*40 + it*4 + q), row rowA[b]
        const unsigned short* Ab = Qb2 + ((size_t)(ksp * 40 + it * 4 + q) * 160) * 8;
        short8 af[5], bf[4];
#pragma unroll
        for (int b = 0; b < 5; ++b)
            af[b] = *(const short8*)(Ab + rowA[b] * 8);
        // B fragments: d-oct of this lane
        int d0 = ksp * 320 + it * 32 + q * 8;
        unsigned du = (unsigned)d0;
        int c = du / 40u, rr = d0 - c * 40;
        int kh0 = rr >> 2;           // even
        const unsigned short* Bb = X + ((size_t)(c * 100 + hk0 + kh0) * 64) * 8;
#pragma unroll
        for (int n = 0; n < 4; ++n)
            bf[n] = *(const short8*)(Bb + (band[n] * 64 + wk[n]) * 8);
#pragma unroll
        for (int b = 0; b < 5; ++b)
#pragma unroll
            for (int n = 0; n < 4; ++n)
                acc[b][n] = __builtin_amdgcn_mfma_f32_16x16x32_bf16(af[b], bf[n], acc[b][n], 0, 0, 0);
    }
    float* base = Sp + (size_t)ksp * (160 * JP_);
#pragma unroll
    for (int b = 0; b < 5; ++b) {
        int i0 = (mh * 5 + b) * 16 + q * 4;
#pragma unroll
        for (int n = 0; n < 4; ++n) {
            int jg = hkt * 128 + (nh * 4 + n) * 16 + l15;
            if (jg < JP_) {
#pragma unroll
                for (int r = 0; r < 4; ++r)
                    base[(size_t)(i0 + r) * JP_ + jg] = acc[b][n][r];
            }
        }
    }
}

// ---------------------------------------------------------------------------
// softmax: per q-row; 16-way vectorized partial sum; writes Atn2 in MFMA-B
// fragment layout Atn2[jp_oct][i][8].
// ---------------------------------------------------------------------------
__global__ __launch_bounds__(256) void softmax_kernel(const float* __restrict__ Sp,
                                                      unsigned short* __restrict__ Atn2) {
    const int i = blockIdx.x;
    const int t = threadIdx.x;
    const int wave = t >> 6, lane = t & 63;
    __shared__ float red[4];
    __shared__ float red2[4];
    f32x4 v[6];
#pragma unroll
    for (int jj = 0; jj < 6; ++jj) {
        int q4 = t + jj * 256;
        f32x4 s = (f32x4){-1e30f, -1e30f, -1e30f, -1e30f};
        if (q4 < 1456) {
            f32x4 a = (f32x4){0.f, 0.f, 0.f, 0.f};
#pragma unroll
            for (int p = 0; p < KS1; ++p)
                a += *(const f32x4*)(Sp + (size_t)p * (160 * JP_) + (size_t)i * JP_ + q4 * 4);
            a *= (1.0f / 5120.0f);
            s = a;
            if (((q4 * 4) & 63) == 60) { s.y = -1e30f; s.z = -1e30f; s.w = -1e30f; }
        }
        v[jj] = s;
    }
    float m = -1e30f;
#pragma unroll
    for (int jj = 0; jj < 6; ++jj)
        m = fmaxf(m, fmaxf(fmaxf(v[jj].x, v[jj].y), fmaxf(v[jj].z, v[jj].w)));
#pragma unroll
    for (int off = 32; off >= 1; off >>= 1) m = fmaxf(m, __shfl_xor(m, off));
    if (lane == 0) red[wave] = m;
    __syncthreads();
    m = fmaxf(fmaxf(red[0], red[1]), fmaxf(red[2], red[3]));

    float s = 0.f;
#pragma unroll
    for (int jj = 0; jj < 6; ++jj) {
#pragma unroll
        for (int e = 0; e < 4; ++e) {
            float x = v[jj][e];
            float r = (x > -1e29f) ? __expf(x - m) : 0.f;
            v[jj][e] = r;
            s += r;
        }
    }
#pragma unroll
    for (int off = 32; off >= 1; off >>= 1) s += __shfl_xor(s, off);
    if (lane == 0) red2[wave] = s;
    __syncthreads();
    float inv = 1.0f / (red2[0] + red2[1] + red2[2] + red2[3]);
#pragma unroll
    for (int jj = 0; jj < 6; ++jj) {
        int q4 = t + jj * 256;
        if (q4 < 1456) {
            short4v u;
            u.x = (short)f2bf(v[jj].x * inv);
            u.y = (short)f2bf(v[jj].y * inv);
            u.z = (short)f2bf(v[jj].z * inv);
            u.w = (short)f2bf(v[jj].w * inv);
            *(short4v*)(Atn2 + ((size_t)(q4 >> 1) * 160 + i) * 8 + (q4 & 1) * 4) = u;
        }
    }
}

// ---------------------------------------------------------------------------
// GEMM2: grid (KS2, 40); tile 128(d) x 160(i). KV^T staged via LDS (Z2s),
// attn B-frags direct from Atn2 (fragment layout).
// ---------------------------------------------------------------------------
__global__ __launch_bounds__(256) void gemm2_kernel(const unsigned short* __restrict__ Atn2,
                                                    const unsigned short* __restrict__ Z2s,
                                                    float* __restrict__ Op) {
    __shared__ short As[128 * 40];   // KV^T tile [d_local][jp_local], stride 40
    const int t = threadIdx.x;
    const int ksp = blockIdx.x;      // 0..15
    const int dt = blockIdx.y;       // 0..39
    const int dbase = dt * 128;
    const int it0 = (182 * ksp) >> 4;
    const int it1 = (182 * (ksp + 1)) >> 4;
    const int wave = t >> 6, lane = t & 63;
    const int mh = wave & 1, nh = wave >> 1;       // wave tile 64(d) x 80(i)
    const int l15 = lane & 15, q = lane >> 4;

    // lane-invariant staging address parts
    const int dl_s = t >> 2, jg_s = t & 3;         // first 512-unit split
    f32x4 acc[4][5];
#pragma unroll
    for (int m = 0; m < 4; ++m)
#pragma unroll
        for (int n = 0; n < 5; ++n) acc[m][n] = (f32x4){0.f, 0.f, 0.f, 0.f};

    for (int it = it0; it < it1; ++it) {
        int k0 = it * 32;
        __syncthreads();
#pragma unroll
        for (int s = 0; s < 2; ++s) {
            int dl = dl_s + s * 64, jg = jg_s;
            int d = dbase + dl;
            unsigned du = (unsigned)d;
            int c = du / 40u, rr = d - c * 40;
            int kh = rr >> 2, kw = rr & 3;
            int jp0 = k0 + jg * 8;
            int hk = jp0 >> 6, wk0 = jp0 & 63;     // wk0 <= 56: in-bounds
            int src = kw * NZ + c * 6400 + (hk + kh) * W_ + wk0;
            *(short8*)&As[dl * 40 + jg * 8] = *(const short8*)(Z2s + src);
        }
        __syncthreads();
        short8 af[4], bf[5];
#pragma unroll
        for (int m = 0; m < 4; ++m)
            af[m] = *(const short8*)&As[(mh * 64 + m * 16 + l15) * 40 + q * 8];
        const unsigned short* Bb = Atn2 + ((size_t)((k0 >> 3) + q) * 160) * 8;
#pragma unroll
        for (int n = 0; n < 5; ++n)
            bf[n] = *(const short8*)(Bb + ((nh * 5 + n) * 16 + l15) * 8);
#pragma unroll
        for (int m = 0; m < 4; ++m)
#pragma unroll
            for (int n = 0; n < 5; ++n)
                acc[m][n] = __builtin_amdgcn_mfma_f32_16x16x32_bf16(af[m], bf[n], acc[m][n], 0, 0, 0);
    }
    float* base = Op + (size_t)ksp * ((size_t)NZ);
#pragma unroll
    for (int m = 0; m < 4; ++m) {
        int d0 = dbase + mh * 64 + m * 16 + q * 4;
#pragma unroll
        for (int n = 0; n < 5; ++n) {
            int i = (nh * 5 + n) * 16 + l15;
#pragma unroll
            for (int r = 0; r < 4; ++r)
                base[(size_t)(d0 + r) * 160 + i] = acc[m][n][r];
        }
    }
}

// ---------------------------------------------------------------------------
// reduce: out[c][ih*10+kh][iw*4+kw] = sum_p Op[p][d*160+i]; vectorized x4
// ---------------------------------------------------------------------------
__global__ __launch_bounds__(256) void reduce_kernel(const float* __restrict__ Op,
                                                     float* __restrict__ out) {
    int tid = blockIdx.x * 256 + threadIdx.x;   // < 204800
    int f = tid * 4;
    f32x4 s = (f32x4){0.f, 0.f, 0.f, 0.f};
#pragma unroll
    for (int p = 0; p < KS2; ++p) s += *(const f32x4*)(Op + (size_t)p * NZ + f);
    int d = f / 160, i0 = f - d * 160;          // i0..i0+3 same d
    int c = d / 40, rr = d - c * 40;
    int kh = rr >> 2, kw = rr & 3;
#pragma unroll
    for (int r = 0; r < 4; ++r) {
        int i = i0 + r;
        int ih = i >> 4, iw = i & 15;
        out[c * 6400 + (ih * KH_ + kh) * W_ + iw * KW_ + kw] = s[r];
    }
}

extern "C" void kernel_launch(void* const* d_in, const int* in_sizes, int n_in,
                              void* d_out, int out_size, void* d_ws, size_t ws_size,
                              hipStream_t stream) {
    const float* z1 = (const float*)d_in[0];
    const float* z2 = (const float*)d_in[1];
    float* out = (float*)d_out;

    char* w = (char*)d_ws;
    unsigned short* Qb2  = (unsigned short*)(w);                 // 1,638,400 B
    unsigned short* Z2s  = (unsigned short*)(w + 1638400);       // 6,553,600 B
    unsigned short* X    = (unsigned short*)(w + 8192000);       // 13,107,200 B
    unsigned short* Atn2 = (unsigned short*)(w + 21299200);      // 1,863,680 B
    float* Sp = (float*)(w + 23162880);                          // 59,637,760 B (16 partials)
    float* Op = Sp;                                              // 52,428,800 B reuse

    pack_kernel<<<5200, 256, 0, stream>>>(z1, z2, Qb2, Z2s, X);
    gemm1_kernel<<<dim3(KS1, 46), 256, 0, stream>>>(Qb2, X, Sp);
    softmax_kernel<<<160, 256, 0, stream>>>(Sp, Atn2);
    gemm2_kernel<<<dim3(KS2, 40), 256, 0, stream>>>(Atn2, Z2s, Op);
    reduce_kernel<<<800, 256, 0, stream>>>(Op, out);
}